// Round 4
// baseline (241.769 us; speedup 1.0000x reference)
//
#include <hip/hip_runtime.h>

#define BDIM 8
#define NPTS 4096
#define KNEI 20
#define BN (BDIM*NPTS)        // 32768
#define NKCNT (NPTS*KNEI)     // 81920
#define EPSI 1e-5f
#define SLOPE 0.01f

typedef __attribute__((ext_vector_type(8))) short bf16x8;
typedef __attribute__((ext_vector_type(4))) float f32x4;
typedef __attribute__((ext_vector_type(4))) unsigned int u32x4;

__device__ __forceinline__ unsigned short f2bf(float f) {
    unsigned u = __builtin_bit_cast(unsigned, f);
    u += 0x7FFFu + ((u >> 16) & 1u);
    return (unsigned short)(u >> 16);
}
__device__ __forceinline__ float bf2f(unsigned short h) {
    unsigned u = ((unsigned)h) << 16;
    return __builtin_bit_cast(float, u);
}

// async global->LDS DMA, 16 B per lane; per-lane global address (gather OK),
// LDS dest = wave-uniform base + lane*16.
__device__ __forceinline__ void async16(const void* g, void* l) {
    __builtin_amdgcn_global_load_lds(
        (const __attribute__((address_space(1))) unsigned int*)g,
        (__attribute__((address_space(3))) unsigned int*)l, 16, 0, 0);
}

// ---------------- K0: u = x*W1a^T, v = x*(W1b-W1a)^T  (bf16 out) ----------------
__global__ __launch_bounds__(256) void k0_uv(const float* __restrict__ x,
        const float* __restrict__ W1, unsigned short* __restrict__ u,
        unsigned short* __restrict__ v) {
    __shared__ float wlds[64 * 129];
    __shared__ float xs[16 * 64];
    int tid = threadIdx.x;
    int m0 = blockIdx.x * 16;
    for (int i = tid; i < 8192; i += 256)
        wlds[(i >> 7) * 129 + (i & 127)] = W1[i];
    for (int i = tid; i < 1024; i += 256)
        xs[i] = x[m0 * 64 + i];
    __syncthreads();
    int o = tid & 63;
    int r0 = tid >> 6;
    float au[4] = {0.f, 0.f, 0.f, 0.f};
    float av[4] = {0.f, 0.f, 0.f, 0.f};
    for (int c = 0; c < 64; ++c) {
        float wa = wlds[o * 129 + c];
        float wb = wlds[o * 129 + 64 + c];
        float wd = wb - wa;
#pragma unroll
        for (int jj = 0; jj < 4; ++jj) {
            float xv = xs[(r0 + jj * 4) * 64 + c];
            au[jj] += xv * wa;
            av[jj] += xv * wd;
        }
    }
#pragma unroll
    for (int jj = 0; jj < 4; ++jj) {
        int m = m0 + r0 + jj * 4;
        u[m * 64 + o] = f2bf(au[jj]);
        v[m * 64 + o] = f2bf(av[jj]);
    }
}

// ---- helper: load A-fragments (W row-major [64][64] fp32 -> bf16 frags) ----
// A[m=l15 -> cout=mt*16+l15][k=q*8+j]
__device__ __forceinline__ void load_bfrags(const float* __restrict__ W,
        int l15, int q, bf16x8 bw[4][2]) {
#pragma unroll
    for (int mt = 0; mt < 4; ++mt)
#pragma unroll
        for (int kc = 0; kc < 2; ++kc) {
            const float* wp = W + (mt * 16 + l15) * 64 + kc * 32 + q * 8;
            bf16x8 t;
#pragma unroll
            for (int j = 0; j < 8; ++j) t[j] = (short)f2bf(wp[j]);
            bw[mt][kc] = t;
        }
}

// ---------------- K1: stats1 of h1 = u[ind]+v, via DMA-gathered LDS tile ----------------
__global__ __launch_bounds__(256) void k1_stats1(const unsigned short* __restrict__ u,
        const unsigned short* __restrict__ v, const int* __restrict__ ind,
        float* __restrict__ s1) {
    __shared__ __align__(16) unsigned char tile[40960];   // 320 rows x 128 B (swizzled)
    __shared__ __align__(16) unsigned char vt[2048];      // 16 rows x 128 B (identity)
    __shared__ int inds[320];
    __shared__ float part[1024];
    int tid = threadIdx.x;
    int lane = tid & 63, w = tid >> 6;
    int b = blockIdx.x >> 8;
    int n0 = (blockIdx.x & 255) << 4;
    int base = b * NPTS + n0;
    int base20 = base * 20;
    for (int i = tid; i < 320; i += 256) inds[i] = ind[base20 + i];
    if (w == 0) {
#pragma unroll
        for (int k = 0; k < 2; ++k)
            async16(v + (size_t)(base + 8 * k + (lane >> 3)) * 64 + (lane & 7) * 8,
                    vt + k * 1024);
    }
    __syncthreads();
    int swz = (lane & 7) ^ ((lane >> 3) & 7);
#pragma unroll
    for (int j = 0; j < 10; ++j) {
        int k = w * 10 + j;
        int r = 8 * k + (lane >> 3);
        int idx = inds[r];
        async16(u + (size_t)idx * 64 + swz * 8, tile + k * 1024);
    }
    __syncthreads();
    int c2 = (tid & 31) * 2;
    int rr = tid >> 5;
    int uoff = (((c2 >> 3) ^ rr) << 4) + ((c2 * 2) & 15);
    float sA = 0.f, qA = 0.f, sB = 0.f, qB = 0.f;
    for (int j = 0; j < 40; ++j) {
        int r = rr + 8 * j;
        int p = (r * 3277) >> 16;
        unsigned uu = *(const unsigned*)(tile + r * 128 + uoff);
        unsigned vv = *(const unsigned*)(vt + p * 128 + c2 * 2);
        float h0 = bf2f((unsigned short)(uu & 0xFFFF)) + bf2f((unsigned short)(vv & 0xFFFF));
        float h1 = bf2f((unsigned short)(uu >> 16)) + bf2f((unsigned short)(vv >> 16));
        sA += h0; qA += h0 * h0;
        sB += h1; qB += h1 * h1;
    }
    part[tid * 4 + 0] = sA; part[tid * 4 + 1] = qA;
    part[tid * 4 + 2] = sB; part[tid * 4 + 3] = qB;
    __syncthreads();
    if (tid < 128) {
        int c = tid & 63, st = tid >> 6;
        float acc = 0.f;
        for (int g = 0; g < 8; ++g)
            acc += part[(g * 32 + (c >> 1)) * 4 + (c & 1) * 2 + st];
        atomicAdd(&s1[st * 512 + b * 64 + c], acc);
    }
}

// ------ K2': gather -> norm1+lrelu -> GEMM2 -> register stats2 (no h2 anywhere) ------
__global__ __launch_bounds__(256) void k2_stats2(const unsigned short* __restrict__ u,
        const unsigned short* __restrict__ v, const int* __restrict__ ind,
        const float* __restrict__ W2, const float* __restrict__ s1,
        float* __restrict__ s2) {
    __shared__ __align__(16) unsigned char tile[40960];   // gather tile, reused as partials
    __shared__ __align__(16) unsigned char vt[2048];
    __shared__ int inds[320];
    int tid = threadIdx.x;
    int lane = tid & 63, w = tid >> 6;
    int l15 = lane & 15, q = lane >> 4;
    int b = blockIdx.x >> 8;
    int n0 = (blockIdx.x & 255) << 4;
    int base = b * NPTS + n0;
    int base20 = base * 20;
    bf16x8 aw[4][2];
    load_bfrags(W2, l15, q, aw);
    const float inv = 1.0f / (float)NKCNT;
    float r1[2][8], mr1[2][8];
#pragma unroll
    for (int kc = 0; kc < 2; ++kc)
#pragma unroll
        for (int j = 0; j < 8; ++j) {
            int c = kc * 32 + q * 8 + j;
            float mm = s1[b * 64 + c] * inv;
            float vv = s1[512 + b * 64 + c] * inv - mm * mm;
            float rs = rsqrtf(vv + EPSI);
            r1[kc][j] = rs; mr1[kc][j] = -mm * rs;
        }
    for (int i = tid; i < 320; i += 256) inds[i] = ind[base20 + i];
    if (w == 0) {
#pragma unroll
        for (int k = 0; k < 2; ++k)
            async16(v + (size_t)(base + 8 * k + (lane >> 3)) * 64 + (lane & 7) * 8,
                    vt + k * 1024);
    }
    __syncthreads();
    int swz = (lane & 7) ^ ((lane >> 3) & 7);
#pragma unroll
    for (int j = 0; j < 10; ++j) {
        int k = w * 10 + j;
        int r = 8 * k + (lane >> 3);
        int idx = inds[r];
        async16(u + (size_t)idx * 64 + swz * 8, tile + k * 1024);
    }
    __syncthreads();
    // B-frags: a1 = lrelu(norm1(u[ind]+v))
    bf16x8 bf[5][2];
#pragma unroll
    for (int nt = 0; nt < 5; ++nt) {
        int row = (w * 5 + nt) * 16 + l15;
        int p = (row * 3277) >> 16;
#pragma unroll
        for (int kc = 0; kc < 2; ++kc) {
            int phys = (((kc * 4 + q) ^ (row & 7)) << 4);
            bf16x8 ub = *(const bf16x8*)(tile + row * 128 + phys);
            bf16x8 vb = *(const bf16x8*)(vt + p * 128 + kc * 64 + q * 16);
            bf16x8 o;
#pragma unroll
            for (int j = 0; j < 8; ++j) {
                float hval = bf2f((unsigned short)ub[j]) + bf2f((unsigned short)vb[j]);
                float t = fmaf(hval, r1[kc][j], mr1[kc][j]);
                t = fmaxf(t, SLOPE * t);
                o[j] = (short)f2bf(t);
            }
            bf[nt][kc] = o;
        }
    }
    // GEMM2, stats in registers: lane's acc[i] is cout = mt*16+q*4+i, row = l15-row
    float ss[16], qq[16];
#pragma unroll
    for (int e = 0; e < 16; ++e) { ss[e] = 0.f; qq[e] = 0.f; }
#pragma unroll
    for (int nt = 0; nt < 5; ++nt) {
#pragma unroll
        for (int mt = 0; mt < 4; ++mt) {
            f32x4 acc = (f32x4){0.f, 0.f, 0.f, 0.f};
            acc = __builtin_amdgcn_mfma_f32_16x16x32_bf16(aw[mt][0], bf[nt][0], acc, 0, 0, 0);
            acc = __builtin_amdgcn_mfma_f32_16x16x32_bf16(aw[mt][1], bf[nt][1], acc, 0, 0, 0);
#pragma unroll
            for (int i = 0; i < 4; ++i) {
                ss[mt * 4 + i] += acc[i];
                qq[mt * 4 + i] = fmaf(acc[i], acc[i], qq[mt * 4 + i]);
            }
        }
    }
    __syncthreads();   // all waves done reading tile; overlay partial arrays
    // partials: [cout][w*16+l15], stride 68 floats (2-way bank alias only)
    float* ssp = (float*)tile;
    float* qqp = ssp + 64 * 68;
#pragma unroll
    for (int e = 0; e < 16; ++e) {
        int cout = (e >> 2) * 16 + q * 4 + (e & 3);
        int idx = cout * 68 + w * 16 + l15;
        ssp[idx] = ss[e]; qqp[idx] = qq[e];
    }
    __syncthreads();
    if (tid < 128) {
        int st = tid >> 6, c = tid & 63;
        const float* arr = st ? qqp : ssp;
        float a = 0.f;
        for (int j = 0; j < 64; ++j)
            a += arr[c * 68 + ((j + c) & 63)];      // rotated: conflict-free
        atomicAdd(&s2[st * 512 + b * 64 + c], a);
    }
}

// -- K3': gather -> a1 -> GEMM2 -> norm2+lrelu (write-side) -> GEMM3 -> max/stats3 -> out --
__global__ __launch_bounds__(256) void k3_gemm3(const unsigned short* __restrict__ u,
        const unsigned short* __restrict__ v, const int* __restrict__ ind,
        const float* __restrict__ W2, const float* __restrict__ W3,
        const float* __restrict__ s1, const float* __restrict__ s2,
        float* __restrict__ s3, float* __restrict__ out) {
    __shared__ __align__(16) unsigned char tile[40960];
    __shared__ __align__(16) unsigned char vt[2048];
    __shared__ int inds[320];
    __shared__ float red[512];
    int tid = threadIdx.x;
    int lane = tid & 63, w = tid >> 6;
    int l15 = lane & 15, q = lane >> 4;
    int b = blockIdx.x >> 8;
    int n0 = (blockIdx.x & 255) << 4;
    int base = b * NPTS + n0;
    int base20 = base * 20;
    bf16x8 aw[4][2];
    load_bfrags(W2, l15, q, aw);
    const float inv = 1.0f / (float)NKCNT;
    float r1[2][8], mr1[2][8];
#pragma unroll
    for (int kc = 0; kc < 2; ++kc)
#pragma unroll
        for (int j = 0; j < 8; ++j) {
            int c = kc * 32 + q * 8 + j;
            float mm = s1[b * 64 + c] * inv;
            float vv = s1[512 + b * 64 + c] * inv - mm * mm;
            float rs = rsqrtf(vv + EPSI);
            r1[kc][j] = rs; mr1[kc][j] = -mm * rs;
        }
    // norm2 params for this lane's C-layout couts: cout = mt*16 + q*4 + i
    float r2c[16], mr2c[16];
#pragma unroll
    for (int e = 0; e < 16; ++e) {
        int c = (e >> 2) * 16 + q * 4 + (e & 3);
        float mm = s2[b * 64 + c] * inv;
        float vv = s2[512 + b * 64 + c] * inv - mm * mm;
        float rs = rsqrtf(vv + EPSI);
        r2c[e] = rs; mr2c[e] = -mm * rs;
    }
    for (int i = tid; i < 320; i += 256) inds[i] = ind[base20 + i];
    if (w == 0) {
#pragma unroll
        for (int k = 0; k < 2; ++k)
            async16(v + (size_t)(base + 8 * k + (lane >> 3)) * 64 + (lane & 7) * 8,
                    vt + k * 1024);
    }
    __syncthreads();
    int swz = (lane & 7) ^ ((lane >> 3) & 7);
#pragma unroll
    for (int j = 0; j < 10; ++j) {
        int k = w * 10 + j;
        int r = 8 * k + (lane >> 3);
        int idx = inds[r];
        async16(u + (size_t)idx * 64 + swz * 8, tile + k * 1024);
    }
    __syncthreads();
    bf16x8 bf[5][2];
#pragma unroll
    for (int nt = 0; nt < 5; ++nt) {
        int row = (w * 5 + nt) * 16 + l15;
        int p = (row * 3277) >> 16;
#pragma unroll
        for (int kc = 0; kc < 2; ++kc) {
            int phys = (((kc * 4 + q) ^ (row & 7)) << 4);
            bf16x8 ub = *(const bf16x8*)(tile + row * 128 + phys);
            bf16x8 vb = *(const bf16x8*)(vt + p * 128 + kc * 64 + q * 16);
            bf16x8 o;
#pragma unroll
            for (int j = 0; j < 8; ++j) {
                float hval = bf2f((unsigned short)ub[j]) + bf2f((unsigned short)vb[j]);
                float t = fmaf(hval, r1[kc][j], mr1[kc][j]);
                t = fmaxf(t, SLOPE * t);
                o[j] = (short)f2bf(t);
            }
            bf[nt][kc] = o;
        }
    }
    __syncthreads();   // all waves done reading gather tile; rewrite it with a2
    // GEMM2 + write-side norm2+lrelu -> a2 into tile (swizzled chunk layout)
#pragma unroll
    for (int nt = 0; nt < 5; ++nt) {
        int row = (w * 5 + nt) * 16 + l15;
        int r7 = row & 7;
#pragma unroll
        for (int mt = 0; mt < 4; ++mt) {
            f32x4 acc = (f32x4){0.f, 0.f, 0.f, 0.f};
            acc = __builtin_amdgcn_mfma_f32_16x16x32_bf16(aw[mt][0], bf[nt][0], acc, 0, 0, 0);
            acc = __builtin_amdgcn_mfma_f32_16x16x32_bf16(aw[mt][1], bf[nt][1], acc, 0, 0, 0);
            unsigned short e0, e1, e2, e3;
            {
                float t0 = fmaf(acc[0], r2c[mt * 4 + 0], mr2c[mt * 4 + 0]); t0 = fmaxf(t0, SLOPE * t0);
                float t1 = fmaf(acc[1], r2c[mt * 4 + 1], mr2c[mt * 4 + 1]); t1 = fmaxf(t1, SLOPE * t1);
                float t2 = fmaf(acc[2], r2c[mt * 4 + 2], mr2c[mt * 4 + 2]); t2 = fmaxf(t2, SLOPE * t2);
                float t3 = fmaf(acc[3], r2c[mt * 4 + 3], mr2c[mt * 4 + 3]); t3 = fmaxf(t3, SLOPE * t3);
                e0 = f2bf(t0); e1 = f2bf(t1); e2 = f2bf(t2); e3 = f2bf(t3);
            }
            unsigned long long pk =
                (unsigned long long)((unsigned)e0 | ((unsigned)e1 << 16)) |
                ((unsigned long long)((unsigned)e2 | ((unsigned)e3 << 16)) << 32);
            int chunk = mt * 2 + (q >> 1);
            int addr = row * 128 + ((chunk ^ r7) << 4) + (q & 1) * 8;
            *(unsigned long long*)(tile + addr) = pk;
        }
    }
    // reuse aw for W3 (loads issue after last W2 use)
    load_bfrags(W3, l15, q, aw);
    __syncthreads();
    // GEMM3: read a2 frags (no VALU norm), write pre-norm h3 back into tile
#pragma unroll
    for (int nt = 0; nt < 5; ++nt) {
        int row = (w * 5 + nt) * 16 + l15;
        int r7 = row & 7;
        bf16x8 b0 = *(const bf16x8*)(tile + row * 128 + (((0 + q) ^ r7) << 4));
        bf16x8 b1 = *(const bf16x8*)(tile + row * 128 + (((4 + q) ^ r7) << 4));
#pragma unroll
        for (int mt = 0; mt < 4; ++mt) {
            f32x4 acc = (f32x4){0.f, 0.f, 0.f, 0.f};
            acc = __builtin_amdgcn_mfma_f32_16x16x32_bf16(aw[mt][0], b0, acc, 0, 0, 0);
            acc = __builtin_amdgcn_mfma_f32_16x16x32_bf16(aw[mt][1], b1, acc, 0, 0, 0);
            unsigned long long pk =
                (unsigned long long)((unsigned)f2bf(acc[0]) | ((unsigned)f2bf(acc[1]) << 16)) |
                ((unsigned long long)((unsigned)f2bf(acc[2]) | ((unsigned)f2bf(acc[3]) << 16)) << 32);
            int chunk = mt * 2 + (q >> 1);
            int addr = row * 128 + ((chunk ^ r7) << 4) + (q & 1) * 8;
            *(unsigned long long*)(tile + addr) = pk;
        }
    }
    __syncthreads();
    // pre-norm max over k=20 + stats3 from completed h3 tile
    {
        int c = tid & 63, p0 = tid >> 6;
        int chunkc = c >> 3, inb = (c & 7) * 2;
        float ssv = 0.f, qsv = 0.f;
#pragma unroll
        for (int ii = 0; ii < 4; ++ii) {
            int p = p0 * 4 + ii;
            float mx = -3.4e38f;
            for (int kk = 0; kk < 20; ++kk) {
                int row = p * 20 + kk;
                float f = bf2f(*(const unsigned short*)(tile + row * 128 +
                             ((chunkc ^ (row & 7)) << 4) + inb));
                mx = fmaxf(mx, f);
                ssv += f; qsv += f * f;
            }
            out[(size_t)(base + p) * 64 + c] = mx;
        }
        red[tid] = ssv; red[256 + tid] = qsv;
    }
    __syncthreads();
    if (tid < 64) {
        float a = 0.f, b2 = 0.f;
        for (int g2 = 0; g2 < 4; ++g2) {
            a  += red[g2 * 64 + tid];
            b2 += red[256 + g2 * 64 + tid];
        }
        atomicAdd(&s3[b * 64 + tid], a);
        atomicAdd(&s3[512 + b * 64 + tid], b2);
    }
}

// ---------------- K4: out = lrelu((out - mean3) * rstd3), in place ----------------
__global__ __launch_bounds__(256) void k4_final(float* __restrict__ out,
        const float* __restrict__ s3) {
    int idx = blockIdx.x * 256 + threadIdx.x;
    int c = idx & 63;
    int b = idx >> 18;
    const float inv = 1.0f / (float)NKCNT;
    float mm = s3[b * 64 + c] * inv;
    float vv = s3[512 + b * 64 + c] * inv - mm * mm;
    float r = rsqrtf(vv + EPSI);
    float val = (out[idx] - mm) * r;
    out[idx] = val >= 0.f ? val : SLOPE * val;
}

extern "C" void kernel_launch(void* const* d_in, const int* in_sizes, int n_in,
                              void* d_out, int out_size, void* d_ws, size_t ws_size,
                              hipStream_t stream) {
    const float* x   = (const float*)d_in[0];
    const int*   ind = (const int*)d_in[1];
    const float* W1  = (const float*)d_in[2];
    const float* W2  = (const float*)d_in[3];
    const float* W3  = (const float*)d_in[4];
    float* out = (float*)d_out;

    unsigned short* u = (unsigned short*)d_ws;            // [32768][64] bf16
    unsigned short* v = u + BN * 64;                      // [32768][64] bf16
    float* stats = (float*)(v + BN * 64);
    float* s1 = stats;          // [2][512]
    float* s2 = stats + 1024;   // [2][512]
    float* s3 = stats + 2048;   // [2][512]

    hipMemsetAsync(stats, 0, 3 * 1024 * sizeof(float), stream);
    k0_uv<<<dim3(BN / 16), dim3(256), 0, stream>>>(x, W1, u, v);
    k1_stats1<<<dim3(BN / 16), dim3(256), 0, stream>>>(u, v, ind, s1);
    k2_stats2<<<dim3(BN / 16), dim3(256), 0, stream>>>(u, v, ind, W2, s1, s2);
    k3_gemm3<<<dim3(BN / 16), dim3(256), 0, stream>>>(u, v, ind, W2, W3, s1, s2, s3, out);
    k4_final<<<dim3(BN * 64 / 256), dim3(256), 0, stream>>>(out, s3);
}